// Round 6
// baseline (32.708 us; speedup 1.0000x reference)
//
#include <hip/hip_runtime.h>
#include <math.h>

// Problem constants (B,C,H,W)=(16,1,1024,1024), patch=128
constexpr int B_ = 16;
constexpr int HW = 1024;
constexpr int NPATCH = 1024;   // 16 samples * 8 * 8
constexpr int NQ = 512;        // quarter-band blocks (16 samples * 8 bands * 4 quarters)
constexpr int T1 = 512;

typedef __attribute__((address_space(3))) unsigned int lds_uint;
typedef __attribute__((address_space(1))) const unsigned int glob_uint;

__device__ __forceinline__ void gload16(const float* g, char* lds_generic) {
    // async global->LDS DMA, 16B/lane; LDS dest = wave-uniform base + lane*16
    __builtin_amdgcn_global_load_lds((glob_uint*)g, (lds_uint*)lds_generic, 16, 0, 0);
}

// Kernel 1: one block per quarter-band (32 rows x 1024 cols, 128KB contiguous
// per array). Per-wave private LDS ring (3 slots), 2 chunks in flight,
// counted vmcnt — no __syncthreads in the stream loop.
__global__ __launch_bounds__(T1)
void stream_kernel(const float* __restrict__ labels,
                   const float* __restrict__ preds,
                   float4* __restrict__ recs)
{
    __shared__ __align__(16) char smem[8 * 3 * 2048];   // 48KB: 8 waves x 3 slots x (1KB x + 1KB t)
    __shared__ float parts[8][2][5];

    const int qid = blockIdx.x;
    const int tid = threadIdx.x;
    const int w = tid >> 6, l = tid & 63;

    const size_t qbase = (size_t)qid * (32 * HW);   // floats; quarters are consecutive slices
    const int lane_off = w * 256 + l * 4;           // floats within an 8KB (2048-float) chunk
    const float* gx = preds  + qbase + lane_off;
    const float* gt = labels + qbase + lane_off;
    char* wslot = smem + w * (3 * 2048);

    // prologue: chunks 0,1 in flight
    #pragma unroll
    for (int c = 0; c < 2; ++c) {
        gload16(gx + c * 2048, wslot + (c % 3) * 2048);
        gload16(gt + c * 2048, wslot + (c % 3) * 2048 + 1024);
    }

    float sum_relu = 0.f, sum_xt = 0.f, sum_l2 = 0.f;
    float xmin = 3.0e38f, xmax = -3.0e38f, tmin = 3.0e38f, tmax = -3.0e38f;
    const float NLOG2E = -1.4426950408889634f; // -log2(e)

    #pragma unroll
    for (int c = 0; c < 16; ++c) {
        if (c + 2 < 16) {
            gload16(gx + (c + 2) * 2048, wslot + ((c + 2) % 3) * 2048);
            gload16(gt + (c + 2) * 2048, wslot + ((c + 2) % 3) * 2048 + 1024);
        }
        // wait for chunk c only: allow chunks c+1,c+2 (2 instr each) in flight
        if (c < 14)       { asm volatile("s_waitcnt vmcnt(4)" ::: "memory"); }
        else if (c == 14) { asm volatile("s_waitcnt vmcnt(2)" ::: "memory"); }
        else              { asm volatile("s_waitcnt vmcnt(0)" ::: "memory"); }
        __builtin_amdgcn_sched_barrier(0);

        const char* xs = wslot + (c % 3) * 2048 + l * 16;
        const float4 x4 = *reinterpret_cast<const float4*>(xs);
        const float4 t4 = *reinterpret_cast<const float4*>(xs + 1024);
        const float xv[4] = {x4.x, x4.y, x4.z, x4.w};
        const float tv[4] = {t4.x, t4.y, t4.z, t4.w};
        #pragma unroll
        for (int j = 0; j < 4; ++j) {
            const float x = xv[j], t = tv[j];
            const float e = __builtin_amdgcn_exp2f(fabsf(x) * NLOG2E);
            sum_l2   += __builtin_amdgcn_logf(1.0f + e);   // v_log_f32 = log2
            sum_relu += fmaxf(x, 0.f);
            sum_xt    = fmaf(x, t, sum_xt);
            xmin = fminf(xmin, x); xmax = fmaxf(xmax, x);
            tmin = fminf(tmin, t); tmax = fmaxf(tmax, t);
        }
    }
    float bce = sum_relu - sum_xt + 0.6931471805599453f * sum_l2;

    // Each 32-lane half of a wave covers exactly one patch's columns.
    #pragma unroll
    for (int o = 16; o > 0; o >>= 1) {
        bce += __shfl_down(bce, o, 32);
        xmin = fminf(xmin, __shfl_down(xmin, o, 32));
        xmax = fmaxf(xmax, __shfl_down(xmax, o, 32));
        tmin = fminf(tmin, __shfl_down(tmin, o, 32));
        tmax = fmaxf(tmax, __shfl_down(tmax, o, 32));
    }
    if ((l & 31) == 0) {
        const int p = 2 * (w & 3) + (l >> 5);   // patch column-block 0..7
        const int j = w >> 2;                   // row-parity contributor 0..1
        parts[p][j][0] = bce;  parts[p][j][1] = xmin; parts[p][j][2] = xmax;
        parts[p][j][3] = tmin; parts[p][j][4] = tmax;
    }
    __syncthreads();
    if (tid < 8) {
        const int p = tid;
        const float b  = parts[p][0][0] + parts[p][1][0];
        const float xi = fminf(parts[p][0][1], parts[p][1][1]);
        const float xa = fmaxf(parts[p][0][2], parts[p][1][2]);
        const float ti = fminf(parts[p][0][3], parts[p][1][3]);
        const float ta = fmaxf(parts[p][0][4], parts[p][1][4]);
        const int s = qid >> 5, q = qid & 31, pb = q >> 2, qq = q & 3;
        const int idx = ((s * 64 + pb * 8 + p) * 4 + qq) * 2;
        recs[idx]     = make_float4(b, xi, xa, 0.f);
        recs[idx + 1] = make_float4(ti, ta, 0.f, 0.f);
    }
}

// Kernel 2: combine 4 quarter-records per patch, apply topo, reduce to scalar.
__global__ __launch_bounds__(1024)
void final_reduce_kernel(const float4* __restrict__ recs, float* __restrict__ out)
{
    const int t = threadIdx.x;   // patch id 0..1023
    float b = 0.f, xi = 3.0e38f, xa = -3.0e38f, ti = 3.0e38f, ta = -3.0e38f;
    #pragma unroll
    for (int qq = 0; qq < 4; ++qq) {
        const float4 rA = recs[(t * 4 + qq) * 2];
        const float4 rB = recs[(t * 4 + qq) * 2 + 1];
        b += rA.x;
        xi = fminf(xi, rA.y); xa = fmaxf(xa, rA.z);
        ti = fminf(ti, rB.x); ta = fmaxf(ta, rB.y);
    }
    float topo = 0.f;
    if (ti < 0.5f && ta > 0.5f) {
        // lh = sigmoid(1-x) decreasing in x: pmax = sig(1-xmin), pmin = sig(1-xmax)
        const float pmax = 1.0f / (1.0f + __expf(xi - 1.0f));
        const float pmin = 1.0f / (1.0f + __expf(xa - 1.0f));
        topo = (pmax - 1.f) * (pmax - 1.f) + pmin * pmin;
    }
    #pragma unroll
    for (int o = 32; o > 0; o >>= 1) {
        b += __shfl_down(b, o);
        topo += __shfl_down(topo, o);
    }
    __shared__ float sb[16], st[16];
    const int wv = t >> 6, ln = t & 63;
    if (ln == 0) { sb[wv] = b; st[wv] = topo; }
    __syncthreads();
    if (t == 0) {
        float bt = 0.f, tt = 0.f;
        #pragma unroll
        for (int i = 0; i < 16; ++i) { bt += sb[i]; tt += st[i]; }
        out[0] = bt / (float)((size_t)B_ * HW * HW) + tt / (float)B_;
    }
}

extern "C" void kernel_launch(void* const* d_in, const int* in_sizes, int n_in,
                              void* d_out, int out_size, void* d_ws, size_t ws_size,
                              hipStream_t stream) {
    const float* labels = (const float*)d_in[0];
    const float* preds  = (const float*)d_in[1];
    float*  out  = (float*)d_out;
    float4* recs = (float4*)d_ws;   // 1024 patches * 4 quarters * 2 float4 = 128KB

    stream_kernel<<<NQ, T1, 0, stream>>>(labels, preds, recs);
    final_reduce_kernel<<<1, 1024, 0, stream>>>(recs, out);
}